// Round 7
// baseline (537.703 us; speedup 1.0000x reference)
//
#include <hip/hip_runtime.h>
#include <hip/hip_cooperative_groups.h>
#include <hip/hip_bf16.h>
#include <math.h>
#include <stdint.h>

namespace cg = cooperative_groups;

#define S_LEN 4096
#define NH 8
#define HD 64
#define NKT 64     // 64-key tiles per sequence
#define MAXC 4     // max K-chunks per q-tile (fallback path layout)
#define NUNITS 1280

typedef __attribute__((ext_vector_type(8))) short bf16x8;
typedef __attribute__((ext_vector_type(4))) short short4v;
typedef __attribute__((ext_vector_type(4))) float f32x4;
typedef __attribute__((ext_vector_type(2))) unsigned uint2v;
typedef __attribute__((ext_vector_type(4))) unsigned uint4v;

__device__ __forceinline__ short f2bf(float f) {
    union { float f; unsigned u; } v; v.f = f;
    unsigned r = (v.u + 0x7fffu + ((v.u >> 16) & 1u)) >> 16;  // RNE fp32->bf16
    return (short)r;
}
__device__ __forceinline__ float bf2f(unsigned short u) {
    union { unsigned u; float f; } v; v.u = ((unsigned)u) << 16;
    return v.f;
}
// pack two fp32 -> two bf16 (round-half-away), 5 VALU ops — hot loop only
__device__ __forceinline__ unsigned pk_bf16(float a, float b) {
    unsigned ua = __builtin_bit_cast(unsigned, a);
    unsigned ub = __builtin_bit_cast(unsigned, b);
    return ((ua + 0x8000u) >> 16) | ((ub + 0x8000u) & 0xffff0000u);
}
__device__ __forceinline__ float fexp2(float x) {
#if __has_builtin(__builtin_amdgcn_exp2f)
    return __builtin_amdgcn_exp2f(x);
#else
    return __expf(x * 0.6931471805599453f);
#endif
}
__device__ __forceinline__ float devload_f32(const float* p) {
    unsigned u = __hip_atomic_load((const unsigned*)p, __ATOMIC_RELAXED, __HIP_MEMORY_SCOPE_AGENT);
    union { unsigned u; float f; } v; v.u = u; return v.f;
}

#if __has_builtin(__builtin_amdgcn_mfma_f32_16x16x16bf16_1k)
__device__ __forceinline__ f32x4 mfma16(short4v a, short4v b, f32x4 c) {
    return __builtin_amdgcn_mfma_f32_16x16x16bf16_1k(a, b, c, 0, 0, 0);
}
#elif __has_builtin(__builtin_amdgcn_mfma_f32_16x16x16_bf16)
__device__ __forceinline__ f32x4 mfma16(short4v a, short4v b, f32x4 c) {
    return __builtin_amdgcn_mfma_f32_16x16x16_bf16(a, b, c, 0, 0, 0);
}
#else
__device__ __forceinline__ f32x4 mfma16(short4v a, short4v b, f32x4 c) {
    bf16x8 a8 = {a[0],a[1],a[2],a[3],0,0,0,0};
    bf16x8 b8 = {b[0],b[1],b[2],b[3],0,0,0,0};
    return __builtin_amdgcn_mfma_f32_16x16x32_bf16(a8, b8, c, 0, 0, 0);
}
#endif

__device__ __forceinline__ void gll16(const void* g, void* l) {
#if __has_builtin(__builtin_amdgcn_global_load_lds)
    __builtin_amdgcn_global_load_lds(
        (const __attribute__((address_space(1))) unsigned int*)(uintptr_t)g,
        (__attribute__((address_space(3))) unsigned int*)(unsigned int)(uintptr_t)l,
        16, 0, 0);
#else
    *(bf16x8*)l = *(const bf16x8*)g;
#endif
}

// =====================================================================
// Single-dispatch cooperative kernel: prep -> attention (work queue) -> merge
// Cross-block data flows ONLY via: (a) fence+grid.sync phase boundaries,
// (b) device-scope atomics. No fences inside hot loops (R4 lesson).
// =====================================================================
__global__ __launch_bounds__(256, 4)
void zz_coop(const float* __restrict__ Q, const float* __restrict__ K,
             const float* __restrict__ V, short* __restrict__ Kbf,
             short* __restrict__ Vtbf, float* __restrict__ Po,
             float* __restrict__ Ml, int* __restrict__ Qcnt,
             float* __restrict__ Out) {
    cg::grid_group gg = cg::this_grid();
    const int tid = threadIdx.x;
    const int bid = blockIdx.x;
    const int gsz = gridDim.x;

    __shared__ __align__(16) char smem[19968];
    __shared__ int s_u;

    // ---------- Phase 0: K/V -> bf16 (+ V transpose), zero accumulators ----------
    {
        short (*Vl)[72] = (short(*)[72])smem;   // 32x72 shorts = 4608 B
        for (int b = bid; b < 1024; b += gsz) {
            const int unit = b >> 1, half = b & 1;
            const int h = unit & 7, kt = unit >> 3;
            const int r2 = tid >> 3, c0 = (tid & 7) * 8;
            const int kk = half * 32 + r2;
            const float* kp = K + ((size_t)(kt*64 + kk)*NH + h)*HD + c0;
            const float* vp = V + ((size_t)(kt*64 + kk)*NH + h)*HD + c0;
            float4 ka = *(const float4*)kp, kb = *(const float4*)(kp + 4);
            float4 va = *(const float4*)vp, vb = *(const float4*)(vp + 4);
            bf16x8 kf8;
            kf8[0]=f2bf(ka.x); kf8[1]=f2bf(ka.y); kf8[2]=f2bf(ka.z); kf8[3]=f2bf(ka.w);
            kf8[4]=f2bf(kb.x); kf8[5]=f2bf(kb.y); kf8[6]=f2bf(kb.z); kf8[7]=f2bf(kb.w);
            *(bf16x8*)&Kbf[((size_t)(h*NKT + kt)*64 + kk)*64 + c0] = kf8;
            short4v v0, v1;
            v0[0]=f2bf(va.x); v0[1]=f2bf(va.y); v0[2]=f2bf(va.z); v0[3]=f2bf(va.w);
            v1[0]=f2bf(vb.x); v1[1]=f2bf(vb.y); v1[2]=f2bf(vb.z); v1[3]=f2bf(vb.w);
            __syncthreads();   // protect Vl from previous iteration's readers
            *(short4v*)&Vl[r2][c0]     = v0;
            *(short4v*)&Vl[r2][c0 + 4] = v1;
            __syncthreads();
            const int d = tid >> 2, j0 = (tid & 3) * 8;
            bf16x8 tv;
            #pragma unroll
            for (int i = 0; i < 8; ++i) tv[i] = Vl[j0 + i][d];
            *(bf16x8*)&Vtbf[((size_t)(h*NKT + kt)*64 + d)*64 + half*32 + j0] = tv;
        }
        // zero Po (2,097,152 floats), Ml (32,768 floats), queue counter
        float4 z4 = {0.f, 0.f, 0.f, 0.f};
        float4* po4 = (float4*)Po;
        for (int i = bid*256 + tid; i < 524288; i += gsz*256) po4[i] = z4;
        for (int i = bid*256 + tid; i < 32768;  i += gsz*256) Ml[i] = 0.f;
        if (bid == 0 && tid == 0) *Qcnt = 0;
    }
    __threadfence();   // release: write back dirty L2 lines before cross-XCD reads
    gg.sync();

    // ---------- Phase 1: attention over global work queue (heavy-first) ----------
    short* Kb = (short*)smem;               // [64 keys][64 d], swizzled 16B blocks
    short* Vt = (short*)(smem + 8192);      // [64 d][64 keys], swizzled
    float* Tb = (float*)smem;               // epilogue: [64 q][68 d] (aliases staging)
    float* Lb = (float*)(smem + 17408);     // epilogue: [16][32] l partials
    float* Lq = (float*)(smem + 19456);     // epilogue: [64] final l

    const int wave = tid >> 6, lane = tid & 63;
    const int l15 = lane & 15, quad = lane >> 4;
    const int kw = wave & 1, qw = wave >> 1;
    const float qscale = 0.125f * 1.4426950408889634f;

    while (true) {
        __syncthreads();                    // prior unit's LDS consumers + s_u done
        if (tid == 0) s_u = atomicAdd(Qcnt, 1);
        __syncthreads();
        const int u = s_u;
        if (u >= NUNITS) break;

        const int h = u & 7;
        const int t = 159 - (u >> 3);       // heavy chunks first
        int qt, c;
        if (t < 16)      { qt = t;               c = 0; }
        else if (t < 48) { qt = 16 + (t-16)/2;   c = (t-16)%2; }
        else if (t < 96) { qt = 32 + (t-48)/3;   c = (t-48)%3; }
        else             { qt = 48 + (t-96)/4;   c = (t-96)%4; }
        const int nc = (qt >> 4) + 1;
        const int k0 = (c * (qt + 1)) / nc;
        const int k1 = ((c + 1) * (qt + 1)) / nc;
        const int qbase = qt * 64;

        // Q fragments (B-operand), scale*log2(e) folded
        bf16x8 qf[2][2];
        #pragma unroll
        for (int nt = 0; nt < 2; ++nt) {
            #pragma unroll
            for (int kc = 0; kc < 2; ++kc) {
                const float* qp = Q + ((size_t)(qbase + qw*32 + nt*16 + l15) * NH + h) * HD + kc*32 + quad*8;
                float4 a = *(const float4*)qp;
                float4 b = *(const float4*)(qp + 4);
                bf16x8 f;
                f[0]=f2bf(a.x*qscale); f[1]=f2bf(a.y*qscale); f[2]=f2bf(a.z*qscale); f[3]=f2bf(a.w*qscale);
                f[4]=f2bf(b.x*qscale); f[5]=f2bf(b.y*qscale); f[6]=f2bf(b.z*qscale); f[7]=f2bf(b.w*qscale);
                qf[nt][kc] = f;
            }
        }

        f32x4 o[4][2];
        #pragma unroll
        for (int dt = 0; dt < 4; ++dt)
            #pragma unroll
            for (int nt = 0; nt < 2; ++nt) o[dt][nt] = (f32x4)0.f;
        float lloc[2] = {0.f, 0.f};

        const short* Ktiles = Kbf  + (size_t)h * NKT * 4096;
        const short* Vtiles = Vtbf + (size_t)h * NKT * 4096;

        for (int kt = k0; kt < k1; ++kt) {
            __syncthreads();
            const char* kg = (const char*)(Ktiles + (size_t)kt * 4096);
            const char* vg = (const char*)(Vtiles + (size_t)kt * 4096);
            #pragma unroll
            for (int i = 0; i < 2; ++i) {
                const int lo = i*4096 + tid*16;
                const int row = lo >> 7, blk = ((lo >> 4) & 7) ^ (row & 7);
                gll16(kg + row*128 + blk*16, (char*)Kb + lo);
            }
            #pragma unroll
            for (int i = 0; i < 2; ++i) {
                const int lo = i*4096 + tid*16;
                const int row = lo >> 7, blk = ((lo >> 4) & 7) ^ (row & 7);
                gll16(vg + row*128 + blk*16, (char*)Vt + lo);
            }
            __syncthreads();

            bf16x8 kf[2][2];
            #pragma unroll
            for (int g = 0; g < 2; ++g) {
                #pragma unroll
                for (int kc = 0; kc < 2; ++kc) {
                    const int row = kw*32 + g*16 + l15;
                    const int blk = (kc*4 + quad) ^ (l15 & 7);
                    kf[g][kc] = *(const bf16x8*)&Kb[row*64 + blk*8];
                }
            }

            short4v pfr[2][2];
            const bool diag = (kt == qt);
            #pragma unroll
            for (int g = 0; g < 2; ++g) {
                #pragma unroll
                for (int nt = 0; nt < 2; ++nt) {
                    f32x4 acc = (f32x4)0.f;
                    acc = __builtin_amdgcn_mfma_f32_16x16x32_bf16(kf[g][0], qf[nt][0], acc, 0, 0, 0);
                    acc = __builtin_amdgcn_mfma_f32_16x16x32_bf16(kf[g][1], qf[nt][1], acc, 0, 0, 0);
                    float pv[4];
                    if (diag) {
                        #pragma unroll
                        for (int r = 0; r < 4; ++r) {
                            const int key = kt*64 + kw*32 + g*16 + quad*4 + r;
                            const int qr  = qbase + qw*32 + nt*16 + l15;
                            pv[r] = (key <= qr) ? fexp2(acc[r]) : 0.f;
                        }
                    } else {
                        #pragma unroll
                        for (int r = 0; r < 4; ++r) pv[r] = fexp2(acc[r]);
                    }
                    lloc[nt] += (pv[0] + pv[1]) + (pv[2] + pv[3]);
                    uint2v uu = { pk_bf16(pv[0], pv[1]), pk_bf16(pv[2], pv[3]) };
                    pfr[g][nt] = __builtin_bit_cast(short4v, uu);
                }
            }

            #pragma unroll
            for (int dt = 0; dt < 4; ++dt) {
                #pragma unroll
                for (int g = 0; g < 2; ++g) {
                    const int row = dt*16 + l15;
                    const int blk = (kw*4 + g*2 + (quad >> 1)) ^ (l15 & 7);
                    short4v vf = *(const short4v*)&Vt[row*64 + blk*8 + (quad & 1)*4];
                    #pragma unroll
                    for (int nt = 0; nt < 2; ++nt)
                        o[dt][nt] = mfma16(vf, pfr[g][nt], o[dt][nt]);
                }
            }
        }

        // epilogue: cross-wave reduce + LDS transpose (R6-proven)
        __syncthreads();
        #pragma unroll
        for (int nt = 0; nt < 2; ++nt)
            Lb[(wave*4 + quad)*32 + nt*16 + l15] = lloc[nt];
        if (kw == 1) {
            #pragma unroll
            for (int dt = 0; dt < 4; ++dt)
                #pragma unroll
                for (int nt = 0; nt < 2; ++nt)
                    *(f32x4*)&Tb[(qw*32 + nt*16 + l15)*68 + dt*16 + quad*4] = o[dt][nt];
        }
        __syncthreads();
        if (kw == 0) {
            #pragma unroll
            for (int dt = 0; dt < 4; ++dt) {
                #pragma unroll
                for (int nt = 0; nt < 2; ++nt) {
                    float* p = &Tb[(qw*32 + nt*16 + l15)*68 + dt*16 + quad*4];
                    f32x4 x = *(f32x4*)p;
                    o[dt][nt] += x;
                    *(f32x4*)p = o[dt][nt];
                }
            }
        }
        if (tid < 64) {
            const int qw2 = tid >> 5, qi = tid & 31;
            float L = 0.f;
            #pragma unroll
            for (int kw2 = 0; kw2 < 2; ++kw2)
                #pragma unroll
                for (int qd = 0; qd < 4; ++qd)
                    L += Lb[((qw2*2 + kw2)*4 + qd)*32 + qi];
            Lq[tid] = L;
        }
        __syncthreads();

        const int q    = tid >> 2;
        const int ds0  = (tid & 3) * 16;
        const int qrow = qbase + q;

        if (nc == 1) {
            // complete result: write Out + lse directly
            const float inv = 1.f / Lq[q];
            const int g2   = qrow >> 9;
            const int rank = (g2 < 4) ? g2 : (7 - g2);
            const int pos  = ((g2 < 4) ? 0 : 512) + (qrow & 511);
            float* op = Out + ((size_t)(rank*1024 + pos)*NH + h)*HD + ds0;
            #pragma unroll
            for (int i = 0; i < 16; i += 4) {
                f32x4 x = *(f32x4*)&Tb[q*68 + ds0 + i];
                op[i+0] = x[0]*inv; op[i+1] = x[1]*inv; op[i+2] = x[2]*inv; op[i+3] = x[3]*inv;
            }
            if (tid < 64) {
                const int qr2  = qbase + tid;
                const int g3   = qr2 >> 9;
                const int rank3 = (g3 < 4) ? g3 : (7 - g3);
                const int pos3  = ((g3 < 4) ? 0 : 512) + (qr2 & 511);
                Out[2097152 + (rank3*8 + h)*1024 + pos3] = __logf(Lq[tid]);
            }
            continue;
        }

        // partial: fp32 atomic accumulation (device-scope, no fences)
        {
            const size_t base = ((size_t)h*4096 + qrow)*64 + ds0;
            #pragma unroll
            for (int i = 0; i < 16; ++i)
                atomicAdd(&Po[base + i], Tb[q*68 + ds0 + i]);
            if (tid < 64)
                atomicAdd(&Ml[h*4096 + qbase + tid], Lq[tid]);
        }
    }

    __threadfence();   // release partials
    gg.sync();

    // ---------- Phase 2: merge qrow >= 1024, normalize, zigzag, lse ----------
    for (int i = bid*256 + tid; i < 8*3072*64; i += gsz*256) {
        const int h    = i / 196608;
        const int rem  = i - h*196608;
        const int qrow = 1024 + (rem >> 6);
        const int d    = rem & 63;
        const float O = devload_f32(&Po[((size_t)h*4096 + qrow)*64 + d]);
        const float L = devload_f32(&Ml[h*4096 + qrow]);
        const int g    = qrow >> 9;
        const int rank = (g < 4) ? g : (7 - g);
        const int pos  = ((g < 4) ? 0 : 512) + (qrow & 511);
        Out[((size_t)(rank*1024 + pos)*NH + h)*HD + d] = O / L;
    }
    for (int i = bid*256 + tid; i < 8*3072; i += gsz*256) {
        const int h    = i / 3072;
        const int qrow = 1024 + (i - h*3072);
        const float L = devload_f32(&Ml[h*4096 + qrow]);
        const int g    = qrow >> 9;
        const int rank = (g < 4) ? g : (7 - g);
        const int pos  = ((g < 4) ? 0 : 512) + (qrow & 511);
        Out[2097152 + (rank*8 + h)*1024 + pos] = __logf(L);
    }
}

// =====================================================================
// Fallback path: R6-proven 3-dispatch pipeline (prep / split / merge)
// =====================================================================
__global__ __launch_bounds__(256)
void zz_prep(const float* __restrict__ K, const float* __restrict__ V,
             short* __restrict__ Kbf, short* __restrict__ Vtbf) {
    const int h = blockIdx.x & 7, kt = blockIdx.x >> 3;
    const int tid = threadIdx.x;
    const int r = tid >> 2, c0 = (tid & 3) * 16;
    __shared__ short Vl[64][72];

    const float* kp = K + ((size_t)(kt * 64 + r) * NH + h) * HD + c0;
    const float* vp = V + ((size_t)(kt * 64 + r) * NH + h) * HD + c0;
    bf16x8 kv0, kv1;
    #pragma unroll
    for (int i = 0; i < 8; i += 4) {
        float4 x = *(const float4*)(kp + i);
        kv0[i+0] = f2bf(x.x); kv0[i+1] = f2bf(x.y); kv0[i+2] = f2bf(x.z); kv0[i+3] = f2bf(x.w);
        float4 x2 = *(const float4*)(kp + 8 + i);
        kv1[i+0] = f2bf(x2.x); kv1[i+1] = f2bf(x2.y); kv1[i+2] = f2bf(x2.z); kv1[i+3] = f2bf(x2.w);
        float4 y = *(const float4*)(vp + i);
        Vl[r][c0+i+0] = f2bf(y.x); Vl[r][c0+i+1] = f2bf(y.y);
        Vl[r][c0+i+2] = f2bf(y.z); Vl[r][c0+i+3] = f2bf(y.w);
        float4 y2 = *(const float4*)(vp + 8 + i);
        Vl[r][c0+8+i+0] = f2bf(y2.x); Vl[r][c0+8+i+1] = f2bf(y2.y);
        Vl[r][c0+8+i+2] = f2bf(y2.z); Vl[r][c0+8+i+3] = f2bf(y2.w);
    }
    short* kout = Kbf + ((size_t)(h * NKT + kt) * 64 + r) * 64 + c0;
    *(bf16x8*)kout = kv0;
    *(bf16x8*)(kout + 8) = kv1;
    __syncthreads();
    bf16x8 tv0, tv1;
    #pragma unroll
    for (int i = 0; i < 8; ++i) { tv0[i] = Vl[c0 + i][r]; tv1[i] = Vl[c0 + 8 + i][r]; }
    short* vout = Vtbf + ((size_t)(h * NKT + kt) * 64 + r) * 64 + c0;
    *(bf16x8*)vout = tv0;
    *(bf16x8*)(vout + 8) = tv1;
}

__global__ __launch_bounds__(256, 4)
void zz_fa_split(const float* __restrict__ Q, const short* __restrict__ Kbf,
                 const short* __restrict__ Vtbf, unsigned short* __restrict__ Po,
                 float* __restrict__ Ml, float* __restrict__ Out) {
    const int h = blockIdx.x & 7;
    const int t = 159 - (blockIdx.x >> 3);
    int qt, c;
    if (t < 16)      { qt = t;               c = 0; }
    else if (t < 48) { qt = 16 + (t-16)/2;   c = (t-16)%2; }
    else if (t < 96) { qt = 32 + (t-48)/3;   c = (t-48)%3; }
    else             { qt = 48 + (t-96)/4;   c = (t-96)%4; }
    const int nc = (qt >> 4) + 1;
    const int k0 = (c * (qt + 1)) / nc;
    const int k1 = ((c + 1) * (qt + 1)) / nc;
    const int qbase = qt * 64;

    const int tid  = threadIdx.x;
    const int wave = tid >> 6;
    const int lane = tid & 63;
    const int l15  = lane & 15;
    const int quad = lane >> 4;
    const int kw   = wave & 1;
    const int qw   = wave >> 1;

    __shared__ __align__(16) char smem[19712];
    short* Kb = (short*)smem;
    short* Vt = (short*)(smem + 8192);
    float* Tb = (float*)smem;
    float* Lb = (float*)(smem + 17408);
    float* Lq = (float*)(smem + 19456);

    const float qscale = 0.125f * 1.4426950408889634f;
    bf16x8 qf[2][2];
    #pragma unroll
    for (int nt = 0; nt < 2; ++nt) {
        #pragma unroll
        for (int kc = 0; kc < 2; ++kc) {
            const float* qp = Q + ((size_t)(qbase + qw*32 + nt*16 + l15) * NH + h) * HD + kc*32 + quad*8;
            float4 a = *(const float4*)qp;
            float4 b = *(const float4*)(qp + 4);
            bf16x8 f;
            f[0]=f2bf(a.x*qscale); f[1]=f2bf(a.y*qscale); f[2]=f2bf(a.z*qscale); f[3]=f2bf(a.w*qscale);
            f[4]=f2bf(b.x*qscale); f[5]=f2bf(b.y*qscale); f[6]=f2bf(b.z*qscale); f[7]=f2bf(b.w*qscale);
            qf[nt][kc] = f;
        }
    }

    f32x4 o[4][2];
    #pragma unroll
    for (int dt = 0; dt < 4; ++dt)
        #pragma unroll
        for (int nt = 0; nt < 2; ++nt) o[dt][nt] = (f32x4)0.f;
    float lloc[2] = {0.f, 0.f};

    const short* Ktiles = Kbf  + (size_t)h * NKT * 4096;
    const short* Vtiles = Vtbf + (size_t)h * NKT * 4096;

    for (int kt = k0; kt < k1; ++kt) {
        __syncthreads();
        const char* kg = (const char*)(Ktiles + (size_t)kt * 4096);
        const char* vg = (const char*)(Vtiles + (size_t)kt * 4096);
        #pragma unroll
        for (int i = 0; i < 2; ++i) {
            const int lo = i*4096 + tid*16;
            const int row = lo >> 7, blk = ((lo >> 4) & 7) ^ (row & 7);
            gll16(kg + row*128 + blk*16, (char*)Kb + lo);
        }
        #pragma unroll
        for (int i = 0; i < 2; ++i) {
            const int lo = i*4096 + tid*16;
            const int row = lo >> 7, blk = ((lo >> 4) & 7) ^ (row & 7);
            gll16(vg + row*128 + blk*16, (char*)Vt + lo);
        }
        __syncthreads();

        bf16x8 kf[2][2];
        #pragma unroll
        for (int g = 0; g < 2; ++g) {
            #pragma unroll
            for (int kc = 0; kc < 2; ++kc) {
                const int row = kw*32 + g*16 + l15;
                const int blk = (kc*4 + quad) ^ (l15 & 7);
                kf[g][kc] = *(const bf16x8*)&Kb[row*64 + blk*8];
            }
        }

        short4v pfr[2][2];
        const bool diag = (kt == qt);
        #pragma unroll
        for (int g = 0; g < 2; ++g) {
            #pragma unroll
            for (int nt = 0; nt < 2; ++nt) {
                f32x4 acc = (f32x4)0.f;
                acc = __builtin_amdgcn_mfma_f32_16x16x32_bf16(kf[g][0], qf[nt][0], acc, 0, 0, 0);
                acc = __builtin_amdgcn_mfma_f32_16x16x32_bf16(kf[g][1], qf[nt][1], acc, 0, 0, 0);
                float pv[4];
                if (diag) {
                    #pragma unroll
                    for (int r = 0; r < 4; ++r) {
                        const int key = kt*64 + kw*32 + g*16 + quad*4 + r;
                        const int qr  = qbase + qw*32 + nt*16 + l15;
                        pv[r] = (key <= qr) ? fexp2(acc[r]) : 0.f;
                    }
                } else {
                    #pragma unroll
                    for (int r = 0; r < 4; ++r) pv[r] = fexp2(acc[r]);
                }
                lloc[nt] += (pv[0] + pv[1]) + (pv[2] + pv[3]);
                uint2v u = { pk_bf16(pv[0], pv[1]), pk_bf16(pv[2], pv[3]) };
                pfr[g][nt] = __builtin_bit_cast(short4v, u);
            }
        }

        #pragma unroll
        for (int dt = 0; dt < 4; ++dt) {
            #pragma unroll
            for (int g = 0; g < 2; ++g) {
                const int row = dt*16 + l15;
                const int blk = (kw*4 + g*2 + (quad >> 1)) ^ (l15 & 7);
                short4v vf = *(const short4v*)&Vt[row*64 + blk*8 + (quad & 1)*4];
                #pragma unroll
                for (int nt = 0; nt < 2; ++nt)
                    o[dt][nt] = mfma16(vf, pfr[g][nt], o[dt][nt]);
            }
        }
    }

    __syncthreads();
    #pragma unroll
    for (int nt = 0; nt < 2; ++nt)
        Lb[(wave*4 + quad)*32 + nt*16 + l15] = lloc[nt];
    if (kw == 1) {
        #pragma unroll
        for (int dt = 0; dt < 4; ++dt)
            #pragma unroll
            for (int nt = 0; nt < 2; ++nt)
                *(f32x4*)&Tb[(qw*32 + nt*16 + l15)*68 + dt*16 + quad*4] = o[dt][nt];
    }
    __syncthreads();
    if (kw == 0) {
        #pragma unroll
        for (int dt = 0; dt < 4; ++dt) {
            #pragma unroll
            for (int nt = 0; nt < 2; ++nt) {
                float* p = &Tb[(qw*32 + nt*16 + l15)*68 + dt*16 + quad*4];
                f32x4 x = *(f32x4*)p;
                o[dt][nt] += x;
                *(f32x4*)p = o[dt][nt];
            }
        }
    }
    if (tid < 64) {
        const int qw2 = tid >> 5, qi = tid & 31;
        float L = 0.f;
        #pragma unroll
        for (int kw2 = 0; kw2 < 2; ++kw2)
            #pragma unroll
            for (int qd = 0; qd < 4; ++qd)
                L += Lb[((qw2*2 + kw2)*4 + qd)*32 + qi];
        Lq[tid] = L;
    }
    __syncthreads();

    const int q    = tid >> 2;
    const int ds0  = (tid & 3) * 16;
    const int qrow = qbase + q;

    if (nc == 1) {
        const float inv = 1.f / Lq[q];
        const int g2   = qrow >> 9;
        const int rank = (g2 < 4) ? g2 : (7 - g2);
        const int pos  = ((g2 < 4) ? 0 : 512) + (qrow & 511);
        float* op = Out + ((size_t)(rank*1024 + pos)*NH + h)*HD + ds0;
        #pragma unroll
        for (int i = 0; i < 16; i += 4) {
            f32x4 x = *(f32x4*)&Tb[q*68 + ds0 + i];
            op[i+0] = x[0]*inv; op[i+1] = x[1]*inv; op[i+2] = x[2]*inv; op[i+3] = x[3]*inv;
        }
        if (tid < 64) {
            const int qr2  = qbase + tid;
            const int g3   = qr2 >> 9;
            const int rank3 = (g3 < 4) ? g3 : (7 - g3);
            const int pos3  = ((g3 < 4) ? 0 : 512) + (qr2 & 511);
            Out[2097152 + (rank3*8 + h)*1024 + pos3] = __logf(Lq[tid]);
        }
        return;
    }

    const size_t bown = (size_t)(h*MAXC + c) * S_LEN;
    {
        uint4v a, b;
        #pragma unroll
        for (int i = 0; i < 4; ++i) {
            a[i] = pk_bf16(Tb[q*68 + ds0 + 2*i],     Tb[q*68 + ds0 + 2*i + 1]);
            b[i] = pk_bf16(Tb[q*68 + ds0 + 8 + 2*i], Tb[q*68 + ds0 + 8 + 2*i + 1]);
        }
        *(uint4v*)&Po[(bown + qrow)*64 + ds0]     = a;
        *(uint4v*)&Po[(bown + qrow)*64 + ds0 + 8] = b;
    }
    if (tid < 64) Ml[bown + qbase + tid] = Lq[tid];
}

__global__ __launch_bounds__(256)
void zz_merge(const unsigned short* __restrict__ Po, const float* __restrict__ Ml,
              float* __restrict__ Out) {
    const int idx  = blockIdx.x * 256 + threadIdx.x;
    const int dq   = idx & 15;
    const int qrow = (idx >> 4) & 4095;
    const int h    = idx >> 16;
    if (qrow < 1024) return;
    const int nc   = (qrow >> 10) + 1;
    const int d0   = dq * 4;

    float L = 0.f;
    f32x4 acc = (f32x4)0.f;
    #pragma unroll 4
    for (int c = 0; c < nc; ++c) {
        const size_t b = (size_t)(h*MAXC + c) * S_LEN + qrow;
        short4v s = *(const short4v*)&Po[b*64 + d0];
        acc[0] += bf2f((unsigned short)s[0]);
        acc[1] += bf2f((unsigned short)s[1]);
        acc[2] += bf2f((unsigned short)s[2]);
        acc[3] += bf2f((unsigned short)s[3]);
        L += Ml[b];
    }
    const float inv = 1.f / L;
    const int g    = qrow >> 9;
    const int rank = (g < 4) ? g : (7 - g);
    const int pos  = ((g < 4) ? 0 : 512) + (qrow & 511);
    float* op = Out + ((size_t)(rank*1024 + pos)*NH + h)*HD + d0;
    f32x4 r = {acc[0]*inv, acc[1]*inv, acc[2]*inv, acc[3]*inv};
    *(f32x4*)op = r;
    if (dq == 0)
        Out[2097152 + (rank*8 + h)*1024 + pos] = __logf(L);
}

// ======== last-resort fallback (R1 mono kernel) if ws too small ========
#define QT 64
#define KT 64
#define LDP 72
__global__ __launch_bounds__(256, 4)
void zz_fa_mono(const float* __restrict__ Q, const float* __restrict__ K,
                const float* __restrict__ V, float* __restrict__ Out) {
    const int h  = blockIdx.x & 7;
    const int qt = 63 - (blockIdx.x >> 3);
    const int qbase = qt * QT;
    const int tid  = threadIdx.x;
    const int wave = tid >> 6;
    const int lane = tid & 63;
    const int l15  = lane & 15;
    const int quad = lane >> 4;

    __shared__ short Kb[KT][LDP];
    __shared__ short Vt[HD][LDP];
    __shared__ short Pb[4][16][LDP];

    const int qrow = qbase + wave * 16 + l15;
    bf16x8 qf[2];
    {
        const float* qp = Q + ((size_t)qrow * NH + h) * HD + quad * 8;
        #pragma unroll
        for (int cc = 0; cc < 2; ++cc) {
            const float* p = qp + cc * 32;
            float4 a = *(const float4*)p;
            float4 b = *(const float4*)(p + 4);
            bf16x8 f;
            f[0]=f2bf(a.x); f[1]=f2bf(a.y); f[2]=f2bf(a.z); f[3]=f2bf(a.w);
            f[4]=f2bf(b.x); f[5]=f2bf(b.y); f[6]=f2bf(b.z); f[7]=f2bf(b.w);
            qf[cc] = f;
        }
    }
    f32x4 o[4];
    #pragma unroll
    for (int nt = 0; nt < 4; ++nt) o[nt] = (f32x4)0.f;
    float m_i[4] = {-INFINITY, -INFINITY, -INFINITY, -INFINITY};
    float l_i[4] = {0.f, 0.f, 0.f, 0.f};
    const int kkK = tid >> 2, dK = (tid & 3) * 16;
    const int kkV = tid & 63, dV = (tid >> 6) * 16;
    const float scale = 0.125f;

    for (int kt = 0; kt <= qt; ++kt) {
        const int kbase = kt * KT;
        __syncthreads();
        {
            const float* kp = K + ((size_t)(kbase + kkK) * NH + h) * HD + dK;
            #pragma unroll
            for (int i = 0; i < 4; ++i) {
                float4 x = *(const float4*)(kp + i * 4);
                short4v s4;
                s4[0]=f2bf(x.x); s4[1]=f2bf(x.y); s4[2]=f2bf(x.z); s4[3]=f2bf(x.w);
                *(short4v*)&Kb[kkK][dK + i * 4] = s4;
            }
        }
        {
            const float* vp = V + ((size_t)(kbase + kkV) * NH + h) * HD + dV;
            #pragma unroll
            for (int i = 0; i < 4; ++i) {
                float4 x = *(const float4*)(vp + i * 4);
                Vt[dV + i*4 + 0][kkV] = f2bf(x.x);
                Vt[dV + i*4 + 1][kkV] = f2bf(x.y);
                Vt[dV + i*4 + 2][kkV] = f2bf(x.z);
                Vt[dV + i*4 + 3][kkV] = f2bf(x.w);
            }
        }
        __syncthreads();
        f32x4 s[4];
        #pragma unroll
        for (int nt = 0; nt < 4; ++nt) {
            f32x4 acc = (f32x4)0.f;
            #pragma unroll
            for (int kc = 0; kc < 2; ++kc) {
                bf16x8 bf = *(const bf16x8*)&Kb[nt*16 + l15][kc*32 + quad*8];
                acc = __builtin_amdgcn_mfma_f32_16x16x32_bf16(qf[kc], bf, acc, 0, 0, 0);
            }
            s[nt] = acc;
        }
        if (kt == qt) {
            #pragma unroll
            for (int nt = 0; nt < 4; ++nt) {
                const int kj = nt*16 + l15;
                #pragma unroll
                for (int r = 0; r < 4; ++r) {
                    const int qi = wave*16 + quad*4 + r;
                    s[nt][r] = (kj <= qi) ? s[nt][r] * scale : -INFINITY;
                }
            }
        } else {
            #pragma unroll
            for (int nt = 0; nt < 4; ++nt)
                #pragma unroll
                for (int r = 0; r < 4; ++r) s[nt][r] *= scale;
        }
        float alpha[4], lsum[4];
        #pragma unroll
        for (int r = 0; r < 4; ++r) {
            float mx = fmaxf(fmaxf(s[0][r], s[1][r]), fmaxf(s[2][r], s[3][r]));
            #pragma unroll
            for (int msk = 1; msk < 16; msk <<= 1)
                mx = fmaxf(mx, __shfl_xor(mx, msk));
            const float mnew = fmaxf(m_i[r], mx);
            alpha[r] = __expf(m_i[r] - mnew);
            m_i[r] = mnew;
            lsum[r] = 0.f;
        }
        #pragma unroll
        for (int nt = 0; nt < 4; ++nt) {
            #pragma unroll
            for (int r = 0; r < 4; ++r) {
                const float p = __expf(s[nt][r] - m_i[r]);
                lsum[r] += p;
                Pb[wave][quad*4 + r][nt*16 + l15] = f2bf(p);
            }
        }
        #pragma unroll
        for (int r = 0; r < 4; ++r) {
            float ls = lsum[r];
            #pragma unroll
            for (int msk = 1; msk < 16; msk <<= 1)
                ls += __shfl_xor(ls, msk);
            l_i[r] = l_i[r] * alpha[r] + ls;
        }
        #pragma unroll
        for (int nt = 0; nt < 4; ++nt)
            #pragma unroll
            for (int r = 0; r < 4; ++r)
                o[nt][r] *= alpha[r];
        bf16x8 pf[2];
        #pragma unroll
        for (int kc = 0; kc < 2; ++kc)
            pf[kc] = *(const bf16x8*)&Pb[wave][l15][kc*32 + quad*8];
        #pragma unroll
        for (int nt = 0; nt < 4; ++nt) {
            #pragma unroll
            for (int kc = 0; kc < 2; ++kc) {
                bf16x8 vf = *(const bf16x8*)&Vt[nt*16 + l15][kc*32 + quad*8];
                o[nt] = __builtin_amdgcn_mfma_f32_16x16x32_bf16(pf[kc], vf, o[nt], 0, 0, 0);
            }
        }
    }
    #pragma unroll
    for (int r = 0; r < 4; ++r) {
        const int qi   = qbase + wave*16 + quad*4 + r;
        const int g    = qi >> 9;
        const int rank = (g < 4) ? g : (7 - g);
        const int pos  = ((g < 4) ? 0 : 512) + (qi & 511);
        const float inv = 1.f / l_i[r];
        float* ob = Out + ((size_t)(rank * 1024 + pos) * NH + h) * HD;
        #pragma unroll
        for (int nt = 0; nt < 4; ++nt)
            ob[nt*16 + l15] = o[nt][r] * inv;
        if (l15 == 0)
            Out[2097152 + (rank*8 + h)*1024 + pos] = m_i[r] + __logf(l_i[r]);
    }
}

extern "C" void kernel_launch(void* const* d_in, const int* in_sizes, int n_in,
                              void* d_out, int out_size, void* d_ws, size_t ws_size,
                              hipStream_t stream) {
    const float* q = (const float*)d_in[0];
    const float* k = (const float*)d_in[1];
    const float* v = (const float*)d_in[2];
    float* out = (float*)d_out;

    const size_t kbf_elems = (size_t)NH * NKT * 64 * 64;          // 2,097,152 shorts each

    // ---- preferred: single cooperative dispatch ----
    {
        const size_t po_f = (size_t)NH * S_LEN * HD;              // 2,097,152 floats
        const size_t ml_f = (size_t)NH * S_LEN;                   // 32,768 floats
        const size_t need = kbf_elems*2*2 + po_f*4 + ml_f*4 + 256; // ~17 MB
        if (ws_size >= need) {
            short* Kbf  = (short*)d_ws;
            short* Vtbf = Kbf + kbf_elems;
            float* Po   = (float*)(Vtbf + kbf_elems);
            float* Ml   = Po + po_f;
            int*   Qcnt = (int*)(Ml + ml_f);
            int nb = 0;
            hipError_t qe = hipOccupancyMaxActiveBlocksPerMultiprocessor(&nb, zz_coop, 256, 0);
            if (qe == hipSuccess && nb > 0) {
                int grid = nb * 256;                // 256 CUs on gfx950
                if (grid > 1280) grid = 1280;
                void* kargs[] = {(void*)&q, (void*)&k, (void*)&v, (void*)&Kbf,
                                 (void*)&Vtbf, (void*)&Po, (void*)&Ml,
                                 (void*)&Qcnt, (void*)&out};
                hipError_t le = hipLaunchCooperativeKernel((void*)zz_coop, dim3(grid),
                                                           dim3(256), kargs, 0, stream);
                if (le == hipSuccess) return;
            }
        }
    }

    // ---- fallback: R6-proven 3-dispatch path ----
    {
        const size_t po_elems  = (size_t)NH * MAXC * S_LEN * HD;
        const size_t ml_elems  = (size_t)NH * MAXC * S_LEN;
        const size_t need = kbf_elems*2*2 + po_elems*2 + ml_elems*4;  // ~25.7 MB
        if (ws_size >= need) {
            short* Kbf  = (short*)d_ws;
            short* Vtbf = Kbf + kbf_elems;
            unsigned short* Po = (unsigned short*)(Vtbf + kbf_elems);
            float* Ml = (float*)(Po + po_elems);
            zz_prep<<<dim3(512), dim3(256), 0, stream>>>(k, v, Kbf, Vtbf);
            zz_fa_split<<<dim3(1280), dim3(256), 0, stream>>>(q, Kbf, Vtbf, Po, Ml, out);
            zz_merge<<<dim3(2048), dim3(256), 0, stream>>>(Po, Ml, out);
            return;
        }
    }
    zz_fa_mono<<<dim3(512), dim3(256), 0, stream>>>(q, k, v, out);
}

// Round 8
// 112.742 us; speedup vs baseline: 4.7693x; 4.7693x over previous
//
#include <hip/hip_runtime.h>
#include <hip/hip_bf16.h>
#include <math.h>
#include <stdint.h>

#define S_LEN 4096
#define NH 8
#define HD 64
#define NKT 64     // 64-key tiles per sequence
#define MAXC 4     // max K-chunks per q-tile

typedef __attribute__((ext_vector_type(8))) short bf16x8;
typedef __attribute__((ext_vector_type(4))) short short4v;
typedef __attribute__((ext_vector_type(4))) float f32x4;
typedef __attribute__((ext_vector_type(2))) unsigned uint2v;
typedef __attribute__((ext_vector_type(4))) unsigned uint4v;

__device__ __forceinline__ short f2bf(float f) {
    union { float f; unsigned u; } v; v.f = f;
    unsigned r = (v.u + 0x7fffu + ((v.u >> 16) & 1u)) >> 16;  // RNE fp32->bf16
    return (short)r;
}
__device__ __forceinline__ float bf2f(unsigned short u) {
    union { unsigned u; float f; } v; v.u = ((unsigned)u) << 16;
    return v.f;
}
// pack two fp32 -> two bf16 (round-half-away), 5 VALU ops — hot loop only
__device__ __forceinline__ unsigned pk_bf16(float a, float b) {
    unsigned ua = __builtin_bit_cast(unsigned, a);
    unsigned ub = __builtin_bit_cast(unsigned, b);
    return ((ua + 0x8000u) >> 16) | ((ub + 0x8000u) & 0xffff0000u);
}
__device__ __forceinline__ float fexp2(float x) {
#if __has_builtin(__builtin_amdgcn_exp2f)
    return __builtin_amdgcn_exp2f(x);
#else
    return __expf(x * 0.6931471805599453f);
#endif
}

#if __has_builtin(__builtin_amdgcn_mfma_f32_16x16x16bf16_1k)
__device__ __forceinline__ f32x4 mfma16(short4v a, short4v b, f32x4 c) {
    return __builtin_amdgcn_mfma_f32_16x16x16bf16_1k(a, b, c, 0, 0, 0);
}
#elif __has_builtin(__builtin_amdgcn_mfma_f32_16x16x16_bf16)
__device__ __forceinline__ f32x4 mfma16(short4v a, short4v b, f32x4 c) {
    return __builtin_amdgcn_mfma_f32_16x16x16_bf16(a, b, c, 0, 0, 0);
}
#else
__device__ __forceinline__ f32x4 mfma16(short4v a, short4v b, f32x4 c) {
    bf16x8 a8 = {a[0],a[1],a[2],a[3],0,0,0,0};
    bf16x8 b8 = {b[0],b[1],b[2],b[3],0,0,0,0};
    return __builtin_amdgcn_mfma_f32_16x16x32_bf16(a8, b8, c, 0, 0, 0);
}
#endif

__device__ __forceinline__ void gll16(const void* g, void* l) {
#if __has_builtin(__builtin_amdgcn_global_load_lds)
    __builtin_amdgcn_global_load_lds(
        (const __attribute__((address_space(1))) unsigned int*)(uintptr_t)g,
        (__attribute__((address_space(3))) unsigned int*)(unsigned int)(uintptr_t)l,
        16, 0, 0);
#else
    *(bf16x8*)l = *(const bf16x8*)g;
#endif
}

// ======== pre-pass: fp32 K,V -> bf16 K[h][kt][kk][d], Vt[h][kt][d][kk] ========
__global__ __launch_bounds__(256)
void zz_prep(const float* __restrict__ K, const float* __restrict__ V,
             short* __restrict__ Kbf, short* __restrict__ Vtbf) {
    const int h = blockIdx.x & 7, kt = blockIdx.x >> 3;
    const int tid = threadIdx.x;
    const int r = tid >> 2, c0 = (tid & 3) * 16;
    __shared__ short Vl[64][72];

    const float* kp = K + ((size_t)(kt * 64 + r) * NH + h) * HD + c0;
    const float* vp = V + ((size_t)(kt * 64 + r) * NH + h) * HD + c0;
    bf16x8 kv0, kv1;
    #pragma unroll
    for (int i = 0; i < 8; i += 4) {
        float4 x = *(const float4*)(kp + i);
        kv0[i+0] = f2bf(x.x); kv0[i+1] = f2bf(x.y); kv0[i+2] = f2bf(x.z); kv0[i+3] = f2bf(x.w);
        float4 x2 = *(const float4*)(kp + 8 + i);
        kv1[i+0] = f2bf(x2.x); kv1[i+1] = f2bf(x2.y); kv1[i+2] = f2bf(x2.z); kv1[i+3] = f2bf(x2.w);
        float4 y = *(const float4*)(vp + i);
        Vl[r][c0+i+0] = f2bf(y.x); Vl[r][c0+i+1] = f2bf(y.y);
        Vl[r][c0+i+2] = f2bf(y.z); Vl[r][c0+i+3] = f2bf(y.w);
        float4 y2 = *(const float4*)(vp + 8 + i);
        Vl[r][c0+8+i+0] = f2bf(y2.x); Vl[r][c0+8+i+1] = f2bf(y2.y);
        Vl[r][c0+8+i+2] = f2bf(y2.z); Vl[r][c0+8+i+3] = f2bf(y2.w);
    }
    short* kout = Kbf + ((size_t)(h * NKT + kt) * 64 + r) * 64 + c0;
    *(bf16x8*)kout = kv0;
    *(bf16x8*)(kout + 8) = kv1;
    __syncthreads();
    bf16x8 tv0, tv1;
    #pragma unroll
    for (int i = 0; i < 8; ++i) { tv0[i] = Vl[c0 + i][r]; tv1[i] = Vl[c0 + 8 + i][r]; }
    short* vout = Vtbf + ((size_t)(h * NKT + kt) * 64 + r) * 64 + c0;
    *(bf16x8*)vout = tv0;
    *(bf16x8*)(vout + 8) = tv1;
}

// ======== split-K flash attention, 2x2 wave layout (R6-proven core) ========
// launch_bounds (256,5): 5 blocks/CU, grid 1280 = 256 CU x 5 -> ALL blocks
// co-resident (no dispatch ramp/tail). Reg budget: ~60 VGPR + 32 AGPR < 102 cap.
__global__ __launch_bounds__(256, 5)
void zz_fa_split(const float* __restrict__ Q, const short* __restrict__ Kbf,
                 const short* __restrict__ Vtbf, unsigned short* __restrict__ Po,
                 float* __restrict__ Ml, float* __restrict__ Out) {
    const int h = blockIdx.x & 7;
    const int t = 159 - (blockIdx.x >> 3);   // heavy chunks first
    int qt, c;
    if (t < 16)      { qt = t;               c = 0; }
    else if (t < 48) { qt = 16 + (t-16)/2;   c = (t-16)%2; }
    else if (t < 96) { qt = 32 + (t-48)/3;   c = (t-48)%3; }
    else             { qt = 48 + (t-96)/4;   c = (t-96)%4; }
    const int nc = (qt >> 4) + 1;
    const int k0 = (c * (qt + 1)) / nc;          // balanced chunks
    const int k1 = ((c + 1) * (qt + 1)) / nc;
    const int qbase = qt * 64;

    const int tid  = threadIdx.x;
    const int wave = tid >> 6;
    const int lane = tid & 63;
    const int l15  = lane & 15;
    const int quad = lane >> 4;
    const int kw   = wave & 1;      // key half
    const int qw   = wave >> 1;     // q half

    __shared__ __align__(16) char smem[19712];
    short* Kb = (short*)smem;               // [64 keys][64 d], swizzled 16B blocks (8 KB)
    short* Vt = (short*)(smem + 8192);      // [64 d][64 keys], swizzled (8 KB)
    float* Tb = (float*)smem;               // epilogue: [64 q][68 d] (17408 B, aliases staging)
    float* Lb = (float*)(smem + 17408);     // epilogue: [16][32] l partials
    float* Lq = (float*)(smem + 19456);     // epilogue: [64] final l

    // ---- Q fragments (B-operand), scale*log2(e) folded ----
    const float qscale = 0.125f * 1.4426950408889634f;
    bf16x8 qf[2][2];
    #pragma unroll
    for (int nt = 0; nt < 2; ++nt) {
        #pragma unroll
        for (int kc = 0; kc < 2; ++kc) {
            const float* qp = Q + ((size_t)(qbase + qw*32 + nt*16 + l15) * NH + h) * HD + kc*32 + quad*8;
            float4 a = *(const float4*)qp;
            float4 b = *(const float4*)(qp + 4);
            bf16x8 f;
            f[0]=f2bf(a.x*qscale); f[1]=f2bf(a.y*qscale); f[2]=f2bf(a.z*qscale); f[3]=f2bf(a.w*qscale);
            f[4]=f2bf(b.x*qscale); f[5]=f2bf(b.y*qscale); f[6]=f2bf(b.z*qscale); f[7]=f2bf(b.w*qscale);
            qf[nt][kc] = f;
        }
    }

    f32x4 o[4][2];    // O^T: [dt][nt]; d = dt*16+quad*4+r, q = qw*32+nt*16+l15
    #pragma unroll
    for (int dt = 0; dt < 4; ++dt)
        #pragma unroll
        for (int nt = 0; nt < 2; ++nt) o[dt][nt] = (f32x4)0.f;
    float lloc[2] = {0.f, 0.f};

    const short* Ktiles = Kbf  + (size_t)h * NKT * 4096;
    const short* Vtiles = Vtbf + (size_t)h * NKT * 4096;

    for (int kt = k0; kt < k1; ++kt) {
        __syncthreads();
        const char* kg = (const char*)(Ktiles + (size_t)kt * 4096);
        const char* vg = (const char*)(Vtiles + (size_t)kt * 4096);
        #pragma unroll
        for (int i = 0; i < 2; ++i) {
            const int lo = i*4096 + tid*16;
            const int row = lo >> 7, blk = ((lo >> 4) & 7) ^ (row & 7);
            gll16(kg + row*128 + blk*16, (char*)Kb + lo);
        }
        #pragma unroll
        for (int i = 0; i < 2; ++i) {
            const int lo = i*4096 + tid*16;
            const int row = lo >> 7, blk = ((lo >> 4) & 7) ^ (row & 7);
            gll16(vg + row*128 + blk*16, (char*)Vt + lo);
        }
        __syncthreads();

        // K fragments: wave's 32 keys in two 16-groups
        bf16x8 kf[2][2];
        #pragma unroll
        for (int g = 0; g < 2; ++g) {
            #pragma unroll
            for (int kc = 0; kc < 2; ++kc) {
                const int row = kw*32 + g*16 + l15;
                const int blk = (kc*4 + quad) ^ (l15 & 7);
                kf[g][kc] = *(const bf16x8*)&Kb[row*64 + blk*8];
            }
        }

        // S^T = K·Q^T (log2 domain), p = exp2(s) in-register
        short4v pfr[2][2];
        const bool diag = (kt == qt);
        #pragma unroll
        for (int g = 0; g < 2; ++g) {
            #pragma unroll
            for (int nt = 0; nt < 2; ++nt) {
                f32x4 acc = (f32x4)0.f;
                acc = __builtin_amdgcn_mfma_f32_16x16x32_bf16(kf[g][0], qf[nt][0], acc, 0, 0, 0);
                acc = __builtin_amdgcn_mfma_f32_16x16x32_bf16(kf[g][1], qf[nt][1], acc, 0, 0, 0);
                float pv[4];
                if (diag) {
                    #pragma unroll
                    for (int r = 0; r < 4; ++r) {
                        const int key = kt*64 + kw*32 + g*16 + quad*4 + r;
                        const int qr  = qbase + qw*32 + nt*16 + l15;
                        pv[r] = (key <= qr) ? fexp2(acc[r]) : 0.f;
                    }
                } else {
                    #pragma unroll
                    for (int r = 0; r < 4; ++r) pv[r] = fexp2(acc[r]);
                }
                lloc[nt] += (pv[0] + pv[1]) + (pv[2] + pv[3]);
                uint2v u = { pk_bf16(pv[0], pv[1]), pk_bf16(pv[2], pv[3]) };
                pfr[g][nt] = __builtin_bit_cast(short4v, u);
            }
        }

        // O^T += V^T · P^T
        #pragma unroll
        for (int dt = 0; dt < 4; ++dt) {
            #pragma unroll
            for (int g = 0; g < 2; ++g) {
                const int row = dt*16 + l15;
                const int blk = (kw*4 + g*2 + (quad >> 1)) ^ (l15 & 7);
                short4v vf = *(const short4v*)&Vt[row*64 + blk*8 + (quad & 1)*4];
                #pragma unroll
                for (int nt = 0; nt < 2; ++nt)
                    o[dt][nt] = mfma16(vf, pfr[g][nt], o[dt][nt]);
            }
        }
    }

    // ---- epilogue: pair-wise cross-wave reduce + LDS transpose (R6-proven) ----
    __syncthreads();   // staging LDS reusable
    #pragma unroll
    for (int nt = 0; nt < 2; ++nt)
        Lb[(wave*4 + quad)*32 + nt*16 + l15] = lloc[nt];
    if (kw == 1) {
        #pragma unroll
        for (int dt = 0; dt < 4; ++dt)
            #pragma unroll
            for (int nt = 0; nt < 2; ++nt)
                *(f32x4*)&Tb[(qw*32 + nt*16 + l15)*68 + dt*16 + quad*4] = o[dt][nt];
    }
    __syncthreads();
    if (kw == 0) {
        #pragma unroll
        for (int dt = 0; dt < 4; ++dt) {
            #pragma unroll
            for (int nt = 0; nt < 2; ++nt) {
                float* p = &Tb[(qw*32 + nt*16 + l15)*68 + dt*16 + quad*4];
                f32x4 x = *(f32x4*)p;
                o[dt][nt] += x;
                *(f32x4*)p = o[dt][nt];
            }
        }
    }
    if (tid < 64) {
        const int qw2 = tid >> 5, qi = tid & 31;
        float L = 0.f;
        #pragma unroll
        for (int kw2 = 0; kw2 < 2; ++kw2)
            #pragma unroll
            for (int qd = 0; qd < 4; ++qd)
                L += Lb[((qw2*2 + kw2)*4 + qd)*32 + qi];
        Lq[tid] = L;
    }
    __syncthreads();   // Tb, Lq final

    const int q    = tid >> 2;
    const int ds0  = (tid & 3) * 16;
    const int qrow = qbase + q;

    if (nc == 1) {
        // single-chunk: write Out directly
        const float inv = 1.f / Lq[q];
        const int g2   = qrow >> 9;
        const int rank = (g2 < 4) ? g2 : (7 - g2);
        const int pos  = ((g2 < 4) ? 0 : 512) + (qrow & 511);
        float* op = Out + ((size_t)(rank*1024 + pos)*NH + h)*HD + ds0;
        #pragma unroll
        for (int i = 0; i < 16; i += 4) {
            f32x4 x = *(f32x4*)&Tb[q*68 + ds0 + i];
            op[i+0] = x[0]*inv; op[i+1] = x[1]*inv; op[i+2] = x[2]*inv; op[i+3] = x[3]*inv;
        }
        if (tid < 64) {
            const int qr2  = qbase + tid;
            const int g3   = qr2 >> 9;
            const int rank3 = (g3 < 4) ? g3 : (7 - g3);
            const int pos3  = ((g3 < 4) ? 0 : 512) + (qr2 & 511);
            Out[2097152 + (rank3*8 + h)*1024 + pos3] = __logf(Lq[tid]);
        }
        return;
    }

    // multi-chunk: write bf16 partials (coalesced via transpose) + l
    const size_t bown = (size_t)(h*MAXC + c) * S_LEN;
    {
        uint4v a, b;
        #pragma unroll
        for (int i = 0; i < 4; ++i) {
            a[i] = pk_bf16(Tb[q*68 + ds0 + 2*i],     Tb[q*68 + ds0 + 2*i + 1]);
            b[i] = pk_bf16(Tb[q*68 + ds0 + 8 + 2*i], Tb[q*68 + ds0 + 8 + 2*i + 1]);
        }
        *(uint4v*)&Po[(bown + qrow)*64 + ds0]     = a;
        *(uint4v*)&Po[(bown + qrow)*64 + ds0 + 8] = b;
    }
    if (tid < 64) Ml[bown + qbase + tid] = Lq[tid];
}

// ======== merge: sum chunk partials for qrow in [1024,4096), normalize, zigzag, lse ========
// grid 1536 x 256: exact work mapping (8 heads x 3072 rows x 16 d-quads), no early-exit waste
__global__ __launch_bounds__(256)
void zz_merge(const unsigned short* __restrict__ Po, const float* __restrict__ Ml,
              float* __restrict__ Out) {
    const int idx  = blockIdx.x * 256 + threadIdx.x;
    const int h    = idx / 49152;            // 3072 rows * 16 quads
    const int rem  = idx - h * 49152;
    const int qrow = 1024 + (rem >> 4);
    const int dq   = rem & 15;
    const int nc   = (qrow >> 10) + 1;
    const int d0   = dq * 4;

    float L = 0.f;
    f32x4 acc = (f32x4)0.f;
    #pragma unroll 4
    for (int c = 0; c < nc; ++c) {
        const size_t b = (size_t)(h*MAXC + c) * S_LEN + qrow;
        short4v s = *(const short4v*)&Po[b*64 + d0];
        acc[0] += bf2f((unsigned short)s[0]);
        acc[1] += bf2f((unsigned short)s[1]);
        acc[2] += bf2f((unsigned short)s[2]);
        acc[3] += bf2f((unsigned short)s[3]);
        L += Ml[b];
    }
    const float inv = 1.f / L;
    const int g    = qrow >> 9;
    const int rank = (g < 4) ? g : (7 - g);
    const int pos  = ((g < 4) ? 0 : 512) + (qrow & 511);
    float* op = Out + ((size_t)(rank*1024 + pos)*NH + h)*HD + d0;
    f32x4 r = {acc[0]*inv, acc[1]*inv, acc[2]*inv, acc[3]*inv};
    *(f32x4*)op = r;
    if (dq == 0)
        Out[2097152 + (rank*8 + h)*1024 + pos] = __logf(L);
}

// ======== fallback (validated R1 mono kernel) if ws too small ========
#define QT 64
#define KT 64
#define LDP 72
__global__ __launch_bounds__(256, 4)
void zz_fa_mono(const float* __restrict__ Q, const float* __restrict__ K,
                const float* __restrict__ V, float* __restrict__ Out) {
    const int h  = blockIdx.x & 7;
    const int qt = 63 - (blockIdx.x >> 3);
    const int qbase = qt * QT;
    const int tid  = threadIdx.x;
    const int wave = tid >> 6;
    const int lane = tid & 63;
    const int l15  = lane & 15;
    const int quad = lane >> 4;

    __shared__ short Kb[KT][LDP];
    __shared__ short Vt[HD][LDP];
    __shared__ short Pb[4][16][LDP];

    const int qrow = qbase + wave * 16 + l15;
    bf16x8 qf[2];
    {
        const float* qp = Q + ((size_t)qrow * NH + h) * HD + quad * 8;
        #pragma unroll
        for (int cc = 0; cc < 2; ++cc) {
            const float* p = qp + cc * 32;
            float4 a = *(const float4*)p;
            float4 b = *(const float4*)(p + 4);
            bf16x8 f;
            f[0]=f2bf(a.x); f[1]=f2bf(a.y); f[2]=f2bf(a.z); f[3]=f2bf(a.w);
            f[4]=f2bf(b.x); f[5]=f2bf(b.y); f[6]=f2bf(b.z); f[7]=f2bf(b.w);
            qf[cc] = f;
        }
    }
    f32x4 o[4];
    #pragma unroll
    for (int nt = 0; nt < 4; ++nt) o[nt] = (f32x4)0.f;
    float m_i[4] = {-INFINITY, -INFINITY, -INFINITY, -INFINITY};
    float l_i[4] = {0.f, 0.f, 0.f, 0.f};
    const int kkK = tid >> 2, dK = (tid & 3) * 16;
    const int kkV = tid & 63, dV = (tid >> 6) * 16;
    const float scale = 0.125f;

    for (int kt = 0; kt <= qt; ++kt) {
        const int kbase = kt * KT;
        __syncthreads();
        {
            const float* kp = K + ((size_t)(kbase + kkK) * NH + h) * HD + dK;
            #pragma unroll
            for (int i = 0; i < 4; ++i) {
                float4 x = *(const float4*)(kp + i * 4);
                short4v s4;
                s4[0]=f2bf(x.x); s4[1]=f2bf(x.y); s4[2]=f2bf(x.z); s4[3]=f2bf(x.w);
                *(short4v*)&Kb[kkK][dK + i * 4] = s4;
            }
        }
        {
            const float* vp = V + ((size_t)(kbase + kkV) * NH + h) * HD + dV;
            #pragma unroll
            for (int i = 0; i < 4; ++i) {
                float4 x = *(const float4*)(vp + i * 4);
                Vt[dV + i*4 + 0][kkV] = f2bf(x.x);
                Vt[dV + i*4 + 1][kkV] = f2bf(x.y);
                Vt[dV + i*4 + 2][kkV] = f2bf(x.z);
                Vt[dV + i*4 + 3][kkV] = f2bf(x.w);
            }
        }
        __syncthreads();
        f32x4 s[4];
        #pragma unroll
        for (int nt = 0; nt < 4; ++nt) {
            f32x4 acc = (f32x4)0.f;
            #pragma unroll
            for (int kc = 0; kc < 2; ++kc) {
                bf16x8 bf = *(const bf16x8*)&Kb[nt*16 + l15][kc*32 + quad*8];
                acc = __builtin_amdgcn_mfma_f32_16x16x32_bf16(qf[kc], bf, acc, 0, 0, 0);
            }
            s[nt] = acc;
        }
        if (kt == qt) {
            #pragma unroll
            for (int nt = 0; nt < 4; ++nt) {
                const int kj = nt*16 + l15;
                #pragma unroll
                for (int r = 0; r < 4; ++r) {
                    const int qi = wave*16 + quad*4 + r;
                    s[nt][r] = (kj <= qi) ? s[nt][r] * scale : -INFINITY;
                }
            }
        } else {
            #pragma unroll
            for (int nt = 0; nt < 4; ++nt)
                #pragma unroll
                for (int r = 0; r < 4; ++r) s[nt][r] *= scale;
        }
        float alpha[4], lsum[4];
        #pragma unroll
        for (int r = 0; r < 4; ++r) {
            float mx = fmaxf(fmaxf(s[0][r], s[1][r]), fmaxf(s[2][r], s[3][r]));
            #pragma unroll
            for (int msk = 1; msk < 16; msk <<= 1)
                mx = fmaxf(mx, __shfl_xor(mx, msk));
            const float mnew = fmaxf(m_i[r], mx);
            alpha[r] = __expf(m_i[r] - mnew);
            m_i[r] = mnew;
            lsum[r] = 0.f;
        }
        #pragma unroll
        for (int nt = 0; nt < 4; ++nt) {
            #pragma unroll
            for (int r = 0; r < 4; ++r) {
                const float p = __expf(s[nt][r] - m_i[r]);
                lsum[r] += p;
                Pb[wave][quad*4 + r][nt*16 + l15] = f2bf(p);
            }
        }
        #pragma unroll
        for (int r = 0; r < 4; ++r) {
            float ls = lsum[r];
            #pragma unroll
            for (int msk = 1; msk < 16; msk <<= 1)
                ls += __shfl_xor(ls, msk);
            l_i[r] = l_i[r] * alpha[r] + ls;
        }
        #pragma unroll
        for (int nt = 0; nt < 4; ++nt)
            #pragma unroll
            for (int r = 0; r < 4; ++r)
                o[nt][r] *= alpha[r];
        bf16x8 pf[2];
        #pragma unroll
        for (int kc = 0; kc < 2; ++kc)
            pf[kc] = *(const bf16x8*)&Pb[wave][l15][kc*32 + quad*8];
        #pragma unroll
        for (int nt = 0; nt < 4; ++nt) {
            #pragma unroll
            for (int kc = 0; kc < 2; ++kc) {
                bf16x8 vf = *(const bf16x8*)&Vt[nt*16 + l15][kc*32 + quad*8];
                o[nt] = __builtin_amdgcn_mfma_f32_16x16x32_bf16(pf[kc], vf, o[nt], 0, 0, 0);
            }
        }
    }
    #pragma unroll
    for (int r = 0; r < 4; ++r) {
        const int qi   = qbase + wave*16 + quad*4 + r;
        const int g    = qi >> 9;
        const int rank = (g < 4) ? g : (7 - g);
        const int pos  = ((g < 4) ? 0 : 512) + (qi & 511);
        const float inv = 1.f / l_i[r];
        float* ob = Out + ((size_t)(rank * 1024 + pos) * NH + h) * HD;
        #pragma unroll
        for (int nt = 0; nt < 4; ++nt)
            ob[nt*16 + l15] = o[nt][r] * inv;
        if (l15 == 0)
            Out[2097152 + (rank*8 + h)*1024 + pos] = m_i[r] + __logf(l_i[r]);
    }
}

extern "C" void kernel_launch(void* const* d_in, const int* in_sizes, int n_in,
                              void* d_out, int out_size, void* d_ws, size_t ws_size,
                              hipStream_t stream) {
    const float* q = (const float*)d_in[0];
    const float* k = (const float*)d_in[1];
    const float* v = (const float*)d_in[2];
    float* out = (float*)d_out;

    const size_t kbf_elems = (size_t)NH * NKT * 64 * 64;          // 2,097,152 shorts each
    const size_t po_elems  = (size_t)NH * MAXC * S_LEN * HD;      // 8,388,608 ushorts
    const size_t ml_elems  = (size_t)NH * MAXC * S_LEN;           // 131,072 floats
    const size_t need = kbf_elems*2*2 + po_elems*2 + ml_elems*4;  // ~25.7 MB

    if (ws_size >= need) {
        short* Kbf  = (short*)d_ws;
        short* Vtbf = Kbf + kbf_elems;
        unsigned short* Po = (unsigned short*)(Vtbf + kbf_elems);
        float* Ml = (float*)(Po + po_elems);
        zz_prep<<<dim3(512), dim3(256), 0, stream>>>(k, v, Kbf, Vtbf);
        zz_fa_split<<<dim3(1280), dim3(256), 0, stream>>>(q, Kbf, Vtbf, Po, Ml, out);
        zz_merge<<<dim3(1536), dim3(256), 0, stream>>>(Po, Ml, out);
    } else {
        zz_fa_mono<<<dim3(512), dim3(256), 0, stream>>>(q, k, v, out);
    }
}